// Round 5
// baseline (4683.625 us; speedup 1.0000x reference)
//
#include <hip/hip_runtime.h>

// Problem constants (T,B,D,H = 512,32,512,512; bidirectional)
#define TT    512
#define BB    32
#define HH    512
#define NBDIR 64           // blocks per direction; each owns 8 hidden units (32 gate rows)
#define NTHR_R 128         // recurrence block: 2 waves

typedef __attribute__((ext_vector_type(8))) short short8;
typedef __attribute__((ext_vector_type(4))) float f32x4;
typedef __attribute__((ext_vector_type(4))) unsigned u32x4;
typedef __attribute__((ext_vector_type(2))) unsigned u32x2;

#define SELH 0x05040100u   // v_perm: dst = [src1.lo16 | src0.lo16<<16]
#define SELL 0x07060302u   // hi16 halves (lo bf16 plane)
#define GOLD 0x9E3779B9u

__device__ __forceinline__ ushort bf16_rne(float v) {
    unsigned u = __builtin_bit_cast(unsigned, v);
    unsigned r = u + 0x7FFFu + ((u >> 16) & 1u);
    return (ushort)(r >> 16);
}
__device__ __forceinline__ float bf16_to_f(ushort h) {
    unsigned u = ((unsigned)h) << 16;
    return __builtin_bit_cast(float, u);
}

// key(s): checksum key for step-s h data. Never 0 for s in [0,512]; poison
// (pay==chk -> xor 0) can never false-accept; s vs s-2 never collide.
__device__ __forceinline__ unsigned keyof(int s) { return (unsigned)(s + 1) * GOLD; }

// coherent tagged load: 16B = 2 x {pay, pay^key}; bypass L1/L2 (MALL)
#define LDT(dst, PB, OFF) \
    asm volatile("global_load_dwordx4 %0, %1, off offset:%c2 sc0 sc1" \
                 : "=v"(dst) : "v"(PB), "i"(OFF) : "memory")
#define LDP4(dst, P) \
    asm volatile("global_load_dwordx4 %0, %1, off" : "=v"(dst) : "v"(P) : "memory")
#define WAIT_VM(N) do { asm volatile("s_waitcnt vmcnt(" #N ")" ::: "memory"); \
                        __builtin_amdgcn_sched_barrier(0); } while (0)

// one sub-chunk: 2 k-steps x 8 elems/lane = 8 x dwordx4 (64 k-elems of h)
#define ISSUE_SUB(BUF, PB, SB) do { \
    LDT(BUF[0], PB, (SB)*512+  0); LDT(BUF[1], PB, (SB)*512+ 16); \
    LDT(BUF[2], PB, (SB)*512+ 32); LDT(BUF[3], PB, (SB)*512+ 48); \
    LDT(BUF[4], PB, (SB)*512+256); LDT(BUF[5], PB, (SB)*512+272); \
    LDT(BUF[6], PB, (SB)*512+288); LDT(BUF[7], PB, (SB)*512+304); \
} while (0)

__device__ __forceinline__ bool sub_ok(const u32x4* buf, unsigned key) {
    unsigned bad = 0u;
    #pragma unroll
    for (int i = 0; i < 8; ++i)
        bad |= (buf[i][0] ^ buf[i][1] ^ key) | (buf[i][2] ^ buf[i][3] ^ key);
    return __all((bad == 0u) ? 1 : 0) != 0;
}
// retry: reissue + full drain (also drains in-flight next sub-chunk — harmless)
#define POLL_SUB(BUF, PB, SB, KEY) \
    while (!sub_ok(BUF, KEY)) { __builtin_amdgcn_s_sleep(1); \
        ISSUE_SUB(BUF, PB, SB); WAIT_VM(0); }

__device__ __forceinline__ void st_tag2(unsigned* p, unsigned pay, unsigned chk) {
    u32x2 v = { pay, chk };
    asm volatile("global_store_dwordx2 %0, %1, off sc0 sc1" :: "v"(p), "v"(v) : "memory");
}
__device__ __forceinline__ void st_f(float* p, float v) {
    asm volatile("global_store_dword %0, %1, off" :: "v"(p), "v"(v) : "memory");
}

// ---------------------------------------------------------------------------
// Pre-pass GEMM: XP[d][blk][t][b][slot] = packed bf16 hi|lo of (x . W_ih^T),
// slot = jl*4 + q for gate g = q*512 + blk*8 + jl (recurrence-block layout).
// ---------------------------------------------------------------------------
__global__ void __launch_bounds__(256, 1)
xpre_gemm(const float* __restrict__ x, const float* __restrict__ W_ih,
          unsigned* __restrict__ XP) {
    __shared__ __align__(16) char sA[32768];   // [128 m][64 k] hi 16K + lo 16K, swizzled
    __shared__ __align__(16) char sB[32768];
    const int tid = threadIdx.x;
    const int bid = blockIdx.x;
    const int d  = bid & 1;
    const int nt = (bid >> 1) & 15;
    const int mt = bid >> 5;
    const int lane = tid & 63, wid = tid >> 6;
    const int wm = wid >> 1, wn = wid & 1;
    const int lr = lane & 15, lk8 = (lane >> 4) * 8;

    f32x4 acc[16];
    #pragma unroll
    for (int i = 0; i < 16; ++i) acc[i] = (f32x4){0.f, 0.f, 0.f, 0.f};

    const float* Ab = x + (size_t)(mt * 128) * 512;
    const float* Bb = W_ih + ((size_t)d * 2048 + nt * 128) * 512;

    for (int kc = 0; kc < 8; ++kc) {
        #pragma unroll
        for (int i = 0; i < 8; ++i) {
            int f = i * 256 + tid;
            int row = f >> 4, fc = f & 15;
            int byte = (row * 128 + fc * 8) ^ ((row & 7) << 4);
            f32x4 va = *(const f32x4*)(Ab + (size_t)row * 512 + kc * 64 + fc * 4);
            f32x4 vb = *(const f32x4*)(Bb + (size_t)row * 512 + kc * 64 + fc * 4);
            ushort h0 = bf16_rne(va[0]), h1 = bf16_rne(va[1]), h2 = bf16_rne(va[2]), h3 = bf16_rne(va[3]);
            ushort l0 = bf16_rne(va[0] - bf16_to_f(h0)), l1 = bf16_rne(va[1] - bf16_to_f(h1));
            ushort l2 = bf16_rne(va[2] - bf16_to_f(h2)), l3 = bf16_rne(va[3] - bf16_to_f(h3));
            *(u32x2*)(sA + byte)         = (u32x2){ (unsigned)h0 | ((unsigned)h1 << 16),
                                                    (unsigned)h2 | ((unsigned)h3 << 16) };
            *(u32x2*)(sA + 16384 + byte) = (u32x2){ (unsigned)l0 | ((unsigned)l1 << 16),
                                                    (unsigned)l2 | ((unsigned)l3 << 16) };
            h0 = bf16_rne(vb[0]); h1 = bf16_rne(vb[1]); h2 = bf16_rne(vb[2]); h3 = bf16_rne(vb[3]);
            l0 = bf16_rne(vb[0] - bf16_to_f(h0)); l1 = bf16_rne(vb[1] - bf16_to_f(h1));
            l2 = bf16_rne(vb[2] - bf16_to_f(h2)); l3 = bf16_rne(vb[3] - bf16_to_f(h3));
            *(u32x2*)(sB + byte)         = (u32x2){ (unsigned)h0 | ((unsigned)h1 << 16),
                                                    (unsigned)h2 | ((unsigned)h3 << 16) };
            *(u32x2*)(sB + 16384 + byte) = (u32x2){ (unsigned)l0 | ((unsigned)l1 << 16),
                                                    (unsigned)l2 | ((unsigned)l3 << 16) };
        }
        __syncthreads();
        #pragma unroll
        for (int ks = 0; ks < 2; ++ks) {
            short8 bh[4], bl[4];
            #pragma unroll
            for (int ns = 0; ns < 4; ++ns) {
                int brow = wn * 64 + ns * 16 + lr;
                int byte = (brow * 128 + (ks * 32 + lk8) * 2) ^ ((brow & 7) << 4);
                bh[ns] = *(const short8*)(sB + byte);
                bl[ns] = *(const short8*)(sB + 16384 + byte);
            }
            #pragma unroll
            for (int ms = 0; ms < 4; ++ms) {
                int arow = wm * 64 + ms * 16 + lr;
                int byte = (arow * 128 + (ks * 32 + lk8) * 2) ^ ((arow & 7) << 4);
                short8 ah = *(const short8*)(sA + byte);
                short8 al = *(const short8*)(sA + 16384 + byte);
                #pragma unroll
                for (int ns = 0; ns < 4; ++ns) {
                    acc[ms*4+ns] = __builtin_amdgcn_mfma_f32_16x16x32_bf16(ah, bh[ns], acc[ms*4+ns], 0,0,0);
                    acc[ms*4+ns] = __builtin_amdgcn_mfma_f32_16x16x32_bf16(al, bh[ns], acc[ms*4+ns], 0,0,0);
                    acc[ms*4+ns] = __builtin_amdgcn_mfma_f32_16x16x32_bf16(ah, bl[ns], acc[ms*4+ns], 0,0,0);
                }
            }
        }
        __syncthreads();
    }
    #pragma unroll
    for (int ms = 0; ms < 4; ++ms)
    #pragma unroll
    for (int ns = 0; ns < 4; ++ns)
    #pragma unroll
    for (int r = 0; r < 4; ++r) {
        float v = acc[ms*4+ns][r];
        int m = mt * 128 + wm * 64 + ms * 16 + (lane >> 4) * 4 + r;
        int n = nt * 128 + wn * 64 + ns * 16 + lr;
        int t = m >> 5, b = m & 31;
        int q = n >> 9, rem = n & 511, bk = rem >> 3, jl = rem & 7;
        ushort hi = bf16_rne(v);
        ushort lo = bf16_rne(v - bf16_to_f(hi));
        XP[((((size_t)d * 64 + bk) * 512 + t) * 32 + b) * 32 + (jl * 4 + q)] =
            (unsigned)hi | ((unsigned)lo << 16);
    }
}

// ---------------------------------------------------------------------------
// Persistent recurrence, flag-free: h exchanged as {pay, pay^key(s)} 8B words
// via MALL (sc0 sc1). Tear-proof: any partial-visibility fails the XOR check
// unless stale==fresh payload (harmless). 128 blocks (2 dir x 64), 128 thr.
// Block owns 8 j (32 gate slots); W_hh slice stationary in LDS (64 KB).
// 8 sub-chunks of 8x16B pipelined 2-deep with exact vmcnt ledger.
// ---------------------------------------------------------------------------
__global__ void __launch_bounds__(NTHR_R, 1)
lstm_persist(const float* __restrict__ h0, const float* __restrict__ c0,
             const float* __restrict__ W_hh, const float* __restrict__ b_ih,
             const float* __restrict__ b_hh, const unsigned* __restrict__ XP,
             unsigned* __restrict__ h_tag, float* __restrict__ out) {
    __shared__ __align__(16) char sW[65536];   // [32 slots][512 k] hi 32K + lo 32K
    __shared__ float sC[32][33];
    __shared__ float sBias[32];

    const int tid = threadIdx.x, bid = blockIdx.x;
    const int d = bid >> 6, blk = bid & 63, j0 = blk * 8;

    for (int idx = tid; idx < 32 * 512; idx += NTHR_R) {
        int r = idx >> 9, col = idx & 511;
        int jl = r >> 2, q = r & 3, g = q * 512 + j0 + jl;
        float v = W_hh[((size_t)d * 2048 + g) * 512 + col];
        ushort hi = bf16_rne(v), lo = bf16_rne(v - bf16_to_f(hi));
        int byte = (r * 1024 + col * 2) ^ ((r & 7) << 4);
        *(ushort*)(sW + byte)         = hi;
        *(ushort*)(sW + 32768 + byte) = lo;
    }
    if (tid < 32) {
        int jl = tid >> 2, q = tid & 3, g = q * 512 + j0 + jl;
        sBias[tid] = b_ih[d * 2048 + g] + b_hh[d * 2048 + g];
    }

    // owned state: thread (b, jl_own) handles jl = jl_own and jl_own+4
    const int b_own = tid >> 2, jl_own = tid & 3;
    float c_reg[2], h_reg[2];
    #pragma unroll
    for (int v = 0; v < 2; ++v) {
        int j = j0 + jl_own + v * 4;
        c_reg[v] = c0[(d * BB + b_own) * HH + j];
        h_reg[v] = h0[(d * BB + b_own) * HH + j];
        ushort hi = bf16_rne(h_reg[v]), lo = bf16_rne(h_reg[v] - bf16_to_f(hi));
        unsigned pay = (unsigned)hi | ((unsigned)lo << 16);
        st_tag2(h_tag + ((size_t)(0 * 2 + d) * 32 + b_own) * 1024 + j * 2,
                pay, pay ^ keyof(0));           // h_0, parity 0
    }
    __syncthreads();

    const int lane = tid & 63, w = tid >> 6;
    const int lr = lane & 15, lk8 = (lane >> 4) * 8;
    const int brow = w * 16 + lr;          // A-rows: waves disjoint (16 b each)

    u32x4 A[8], B[8];

    for (int s = 0; s < TT; ++s) {
        const int t_eff = d ? (TT - 1 - s) : s;
        const int p = s & 1;
        const unsigned key  = keyof(s);
        const unsigned nkey = keyof(s + 1);

        // XP prefetch (plain cached; oldest ledger entries with prev stores)
        const unsigned* xpb =
            XP + ((((size_t)d * 64 + blk) * 512 + t_eff) * 32 + b_own) * 32;
        u32x4 xpA, xpB;
        LDP4(xpA, xpb + jl_own * 4);
        LDP4(xpB, xpb + (jl_own + 4) * 4);

        // per-lane tagged-h base: row brow, first elem lk8
        const unsigned* pb =
            h_tag + ((size_t)(p * 2 + d) * 32 + brow) * 1024 + lk8 * 2;

        f32x4 acc0 = {0.f, 0.f, 0.f, 0.f}, acc1 = acc0;

        auto mfma_sub = [&](const u32x4* buf, int sb) {
            #pragma unroll
            for (int ksl = 0; ksl < 2; ++ksl) {
                unsigned p0 = buf[ksl*4+0][0], p1 = buf[ksl*4+0][2];
                unsigned p2 = buf[ksl*4+1][0], p3 = buf[ksl*4+1][2];
                unsigned p4 = buf[ksl*4+2][0], p5 = buf[ksl*4+2][2];
                unsigned p6 = buf[ksl*4+3][0], p7 = buf[ksl*4+3][2];
                u32x4 hh = { __builtin_amdgcn_perm(p1, p0, SELH), __builtin_amdgcn_perm(p3, p2, SELH),
                             __builtin_amdgcn_perm(p5, p4, SELH), __builtin_amdgcn_perm(p7, p6, SELH) };
                u32x4 ll = { __builtin_amdgcn_perm(p1, p0, SELL), __builtin_amdgcn_perm(p3, p2, SELL),
                             __builtin_amdgcn_perm(p5, p4, SELL), __builtin_amdgcn_perm(p7, p6, SELL) };
                short8 ah = __builtin_bit_cast(short8, hh);
                short8 al = __builtin_bit_cast(short8, ll);
                int k2 = (sb * 64 + ksl * 32 + lk8) * 2;
                {   int byte = (lr * 1024 + k2) ^ ((lr & 7) << 4);
                    short8 bh = *(const short8*)(sW + byte);
                    short8 bl = *(const short8*)(sW + 32768 + byte);
                    acc0 = __builtin_amdgcn_mfma_f32_16x16x32_bf16(ah, bh, acc0, 0,0,0);
                    acc0 = __builtin_amdgcn_mfma_f32_16x16x32_bf16(al, bh, acc0, 0,0,0);
                    acc0 = __builtin_amdgcn_mfma_f32_16x16x32_bf16(ah, bl, acc0, 0,0,0);
                }
                {   int srow = 16 + lr;
                    int byte = (srow * 1024 + k2) ^ ((srow & 7) << 4);
                    short8 bh = *(const short8*)(sW + byte);
                    short8 bl = *(const short8*)(sW + 32768 + byte);
                    acc1 = __builtin_amdgcn_mfma_f32_16x16x32_bf16(ah, bh, acc1, 0,0,0);
                    acc1 = __builtin_amdgcn_mfma_f32_16x16x32_bf16(al, bh, acc1, 0,0,0);
                    acc1 = __builtin_amdgcn_mfma_f32_16x16x32_bf16(ah, bl, acc1, 0,0,0);
                }
            }
        };

        // 8 sub-chunks, 2-deep pipeline; ledger: 4 prev stores + 2 XP are the
        // oldest entries, drained by the first WAIT_VM(8).
        ISSUE_SUB(A, pb, 0);
        ISSUE_SUB(B, pb, 1);
        WAIT_VM(8); POLL_SUB(A, pb, 0, key); mfma_sub(A, 0);
        ISSUE_SUB(A, pb, 2);
        WAIT_VM(8); POLL_SUB(B, pb, 1, key); mfma_sub(B, 1);
        ISSUE_SUB(B, pb, 3);
        WAIT_VM(8); POLL_SUB(A, pb, 2, key); mfma_sub(A, 2);
        ISSUE_SUB(A, pb, 4);
        WAIT_VM(8); POLL_SUB(B, pb, 3, key); mfma_sub(B, 3);
        ISSUE_SUB(B, pb, 5);
        WAIT_VM(8); POLL_SUB(A, pb, 4, key); mfma_sub(A, 4);
        ISSUE_SUB(A, pb, 6);
        WAIT_VM(8); POLL_SUB(B, pb, 5, key); mfma_sub(B, 5);
        ISSUE_SUB(B, pb, 7);
        WAIT_VM(8); POLL_SUB(A, pb, 6, key); mfma_sub(A, 6);
        WAIT_VM(0); POLL_SUB(B, pb, 7, key); mfma_sub(B, 7);

        // C layout: row = b (wave-local), col = slot
        #pragma unroll
        for (int r = 0; r < 4; ++r) {
            int row = w * 16 + (lane >> 4) * 4 + r;
            sC[row][lr]      = acc0[r];
            sC[row][16 + lr] = acc1[r];
        }
        __syncthreads();

        const int pn = (s + 1) & 1;
        #pragma unroll
        for (int v = 0; v < 2; ++v) {
            int jl = jl_own + v * 4;
            u32x4 xp = v ? xpB : xpA;
            float gi = sC[b_own][jl*4+0] + sBias[jl*4+0]
                     + bf16_to_f((ushort)(xp[0] & 0xFFFF)) + bf16_to_f((ushort)(xp[0] >> 16));
            float gf = sC[b_own][jl*4+1] + sBias[jl*4+1]
                     + bf16_to_f((ushort)(xp[1] & 0xFFFF)) + bf16_to_f((ushort)(xp[1] >> 16));
            float gg = sC[b_own][jl*4+2] + sBias[jl*4+2]
                     + bf16_to_f((ushort)(xp[2] & 0xFFFF)) + bf16_to_f((ushort)(xp[2] >> 16));
            float go = sC[b_own][jl*4+3] + sBias[jl*4+3]
                     + bf16_to_f((ushort)(xp[3] & 0xFFFF)) + bf16_to_f((ushort)(xp[3] >> 16));
            float ig = 1.f / (1.f + expf(-gi));
            float fg = 1.f / (1.f + expf(-gf));
            float gt = tanhf(gg);
            float og = 1.f / (1.f + expf(-go));
            c_reg[v] = fg * c_reg[v] + ig * gt;
            h_reg[v] = og * tanhf(c_reg[v]);

            int j = j0 + jl;
            ushort hi = bf16_rne(h_reg[v]), lo = bf16_rne(h_reg[v] - bf16_to_f(hi));
            unsigned pay = (unsigned)hi | ((unsigned)lo << 16);
            st_tag2(h_tag + ((size_t)(pn * 2 + d) * 32 + b_own) * 1024 + j * 2,
                    pay, pay ^ nkey);
            st_f(out + ((size_t)t_eff * BB + b_own) * 1024 + d * 512 + j, h_reg[v]);
        }
        // no trailing barrier: peers' reads of our h_{s-1} are complete by the
        // time their step-s data is visible (checked via XOR keys).
    }

    #pragma unroll
    for (int v = 0; v < 2; ++v) {
        int j = j0 + jl_own + v * 4;
        out[16777216 +         (d * BB + b_own) * HH + j] = h_reg[v];
        out[16777216 + 32768 + (d * BB + b_own) * HH + j] = c_reg[v];
    }
}

extern "C" void kernel_launch(void* const* d_in, const int* in_sizes, int n_in,
                              void* d_out, int out_size, void* d_ws, size_t ws_size,
                              hipStream_t stream) {
    const float* x    = (const float*)d_in[0];
    const float* h0   = (const float*)d_in[1];
    const float* c0   = (const float*)d_in[2];
    const float* W_ih = (const float*)d_in[3];
    const float* b_ih = (const float*)d_in[4];
    const float* W_hh = (const float*)d_in[5];
    const float* b_hh = (const float*)d_in[6];
    float* out = (float*)d_out;

    // ws: XP (256 MiB packed u32) | h_tag (2 parity x 2 dir x 32 b x 512 j x 8B)
    unsigned* XP    = (unsigned*)d_ws;
    unsigned* h_tag = XP + (size_t)2 * 64 * 512 * 32 * 32;

    xpre_gemm<<<4096, 256, 0, stream>>>(x, W_ih, XP);

    void* args[] = { &h0, &c0, &W_hh, &b_ih, &b_hh, &XP, &h_tag, &out };
    hipLaunchCooperativeKernel((void*)lstm_persist, dim3(2 * NBDIR), dim3(NTHR_R),
                               args, 0, stream);
}